// Round 1
// baseline (122.185 us; speedup 1.0000x reference)
//
#include <hip/hip_runtime.h>

#define GRIDN 31
#define ROW   961      // 31*31
#define BJ    65536    // 1024 * 64
#define NBLOCKS 2048
#define WAVES_PER_BLOCK 4
#define ROWS_PER_WAVE (BJ / (NBLOCKS * WAVES_PER_BLOCK))   // 8

__global__ __launch_bounds__(256) void soft_argmax_loss_kernel(
    const float* __restrict__ pred,
    const float* __restrict__ gt,
    float* __restrict__ out)
{
    const int lane = threadIdx.x & 63;
    const int wave = threadIdx.x >> 6;
    const int gw   = blockIdx.x * WAVES_PER_BLOCK + wave;   // 0..8191

    float wsum = 0.0f;

    #pragma unroll 1
    for (int rr = 0; rr < ROWS_PER_WAVE; ++rr) {
        const int r = gw * ROWS_PER_WAVE + rr;
        const float* __restrict__ p = pred + (size_t)r * ROW;
        const float* __restrict__ g = gt   + (size_t)r * ROW;

        float dx = 0.0f, dy = 0.0f;
        // coordinates of element index i: x = i % 31, y = i / 31
        int x = lane % GRIDN;
        int y = lane / GRIDN;

        for (int i = lane; i < ROW; i += 64) {
            float d = p[i] - g[i];
            dx = fmaf(d, (float)x, dx);
            dy = fmaf(d, (float)y, dy);
            // advance by 64: 64 = 2*31 + 2
            x += 2; y += 2;
            if (x >= GRIDN) { x -= GRIDN; y += 1; }
        }

        // wave butterfly reduce (all lanes end with the full sum)
        #pragma unroll
        for (int off = 32; off; off >>= 1) {
            dx += __shfl_xor(dx, off);
            dy += __shfl_xor(dy, off);
        }

        // px - tx = dx / 31 ; py - ty = dy / 31 ; dist = sqrt(...)/2
        float ddx = dx * (1.0f / 31.0f);
        float ddy = dy * (1.0f / 31.0f);
        wsum += 0.5f * sqrtf(ddx * ddx + ddy * ddy);
    }

    __shared__ float s[WAVES_PER_BLOCK];
    if (lane == 0) s[wave] = wsum;
    __syncthreads();
    if (threadIdx.x == 0) {
        float t = (s[0] + s[1] + s[2] + s[3]) * (1.0f / (float)BJ);
        atomicAdd(out, t);
    }
}

extern "C" void kernel_launch(void* const* d_in, const int* in_sizes, int n_in,
                              void* d_out, int out_size, void* d_ws, size_t ws_size,
                              hipStream_t stream) {
    const float* pred = (const float*)d_in[0];
    const float* gt   = (const float*)d_in[1];
    float* out = (float*)d_out;

    // d_out is poisoned once and never re-poisoned between replays: zero it
    // every launch (async memset is graph-capture safe).
    hipMemsetAsync(out, 0, sizeof(float), stream);

    soft_argmax_loss_kernel<<<NBLOCKS, 256, 0, stream>>>(pred, gt, out);
}

// Round 2
// 96.850 us; speedup vs baseline: 1.2616x; 1.2616x over previous
//
#include <hip/hip_runtime.h>

#define GRIDN 31
#define ROW   961            // 31*31
#define BJ    65536          // 1024 * 64 rows
#define NPAIRS (BJ / 2)      // 32768 row-pairs, each 1922 floats = 961 float2
#define NBLOCKS 2048
#define WPB 4                // waves per block
#define PAIRS_PER_WAVE (NPAIRS / (NBLOCKS * WPB))   // 4

__global__ __launch_bounds__(256) void soft_argmax_loss_kernel(
    const float* __restrict__ pred,
    const float* __restrict__ gt,
    float* __restrict__ out)
{
    const int lane = threadIdx.x & 63;
    const int wave = threadIdx.x >> 6;
    const int gw   = blockIdx.x * WPB + wave;       // 0..8191

    // ---- hoisted weights: fixed per (lane, k, c) across ALL pairs ----
    // slot j = lane + 64k covers elements e = 2j, 2j+1 of the 1922-elem pair.
    // e < 961 -> row A, e >= 961 -> row B with e' = e - 961.
    // (e == 961 has (x,y) = (0,0): zero contribution, routing irrelevant.)
    float wx[16][2], wy[16][2];
    #pragma unroll
    for (int k = 0; k < 16; ++k) {
        const int j = lane + 64 * k;
        #pragma unroll
        for (int c = 0; c < 2; ++c) {
            int e  = 2 * j + c;
            int ep = (e >= ROW) ? (e - ROW) : e;
            int y  = ep / GRIDN;
            int x  = ep - GRIDN * y;
            bool valid = (j <= 960);                 // k=15: only lane 0 real
            wx[k][c] = valid ? (float)x : 0.0f;
            wy[k][c] = valid ? (float)y : 0.0f;
        }
    }

    const float2* __restrict__ p2 = (const float2*)pred;
    const float2* __restrict__ g2 = (const float2*)gt;

    float wsum = 0.0f;

    #pragma unroll 1
    for (int pr = 0; pr < PAIRS_PER_WAVE; ++pr) {
        const int P = gw * PAIRS_PER_WAVE + pr;
        const size_t base = (size_t)P * ROW;         // in float2 units

        float dxA = 0.f, dyA = 0.f;                  // row 2P
        float dxM = 0.f, dyM = 0.f;                  // k==7 mixed slot
        float dxB = 0.f, dyB = 0.f;                  // row 2P+1

        #pragma unroll
        for (int k = 0; k < 16; ++k) {
            const int j  = lane + 64 * k;
            const int jc = (k == 15) ? 960 : j;      // clamp tail (weights 0 off-lane0)
            float2 pv = p2[base + jc];
            float2 gv = g2[base + jc];
            float d0 = pv.x - gv.x;
            float d1 = pv.y - gv.y;
            if (k <= 6) {
                dxA = fmaf(d0, wx[k][0], dxA); dyA = fmaf(d0, wy[k][0], dyA);
                dxA = fmaf(d1, wx[k][1], dxA); dyA = fmaf(d1, wy[k][1], dyA);
            } else if (k == 7) {
                dxM = fmaf(d0, wx[k][0], dxM); dyM = fmaf(d0, wy[k][0], dyM);
                dxM = fmaf(d1, wx[k][1], dxM); dyM = fmaf(d1, wy[k][1], dyM);
            } else {
                dxB = fmaf(d0, wx[k][0], dxB); dyB = fmaf(d0, wy[k][0], dyB);
                dxB = fmaf(d1, wx[k][1], dxB); dyB = fmaf(d1, wy[k][1], dyB);
            }
        }

        // route the mixed k==7 slot: lanes 0..32 -> row A, 33..63 -> row B
        const bool toA = (lane <= 32);
        dxA += toA ? dxM : 0.f;  dyA += toA ? dyM : 0.f;
        dxB += toA ? 0.f : dxM;  dyB += toA ? 0.f : dyM;

        // wave butterfly reduce (4 values)
        #pragma unroll
        for (int off = 32; off; off >>= 1) {
            dxA += __shfl_xor(dxA, off); dyA += __shfl_xor(dyA, off);
            dxB += __shfl_xor(dxB, off); dyB += __shfl_xor(dyB, off);
        }

        const float s31 = 1.0f / 31.0f;
        float ax = dxA * s31, ay = dyA * s31;
        float bx = dxB * s31, by = dyB * s31;
        wsum += 0.5f * (sqrtf(ax * ax + ay * ay) + sqrtf(bx * bx + by * by));
    }

    __shared__ float s[WPB];
    if (lane == 0) s[wave] = wsum;
    __syncthreads();
    if (threadIdx.x == 0) {
        atomicAdd(out, (s[0] + s[1] + s[2] + s[3]) * (1.0f / (float)BJ));
    }
}

extern "C" void kernel_launch(void* const* d_in, const int* in_sizes, int n_in,
                              void* d_out, int out_size, void* d_ws, size_t ws_size,
                              hipStream_t stream) {
    const float* pred = (const float*)d_in[0];
    const float* gt   = (const float*)d_in[1];
    float* out = (float*)d_out;

    // d_out is poisoned once and never re-poisoned between replays: zero it
    // every launch (async memset is graph-capture safe).
    hipMemsetAsync(out, 0, sizeof(float), stream);

    soft_argmax_loss_kernel<<<NBLOCKS, 256, 0, stream>>>(pred, gt, out);
}